// Round 8
// baseline (1571.147 us; speedup 1.0000x reference)
//
#include <hip/hip_runtime.h>
#include <stdint.h>

#define TB     400
#define OUTROW 160000   // T * 2F
#define NTHR   512
#define GRID   16       // (dir 2) x (seq-group 8), 16 seqs per block

typedef _Float16 f16x8 __attribute__((ext_vector_type(8)));
typedef float    f32x4 __attribute__((ext_vector_type(4)));
typedef uint16_t u16;
typedef uint32_t u32;

__device__ __forceinline__ float sigf(float x){ return 1.0f/(1.0f+__expf(-x)); }
__device__ __forceinline__ float tanhf_(float x){ float e=__expf(2.0f*x); return 1.0f-2.0f/(e+1.0f); }
__device__ __forceinline__ u16 h16(float x){ _Float16 h=(_Float16)x; return __builtin_bit_cast(u16,h); }

// x~ layout: k 0..99 = x, 100..299 = m, 300..319 = zero pad. 10 K-tiles of 32.
// A-frag element (seq m, k): tile kt=k>>5, lane = m | (((k>>3)&3)<<4), half j=k&7.
// Gate N-tiles (25): wave0 {0,8,16,24}; wave w {w,w+8,w+16}.
// Proj: K=100 pad 128 (4 K-tiles); N=200 pad 208 (13 tiles): waves 1..6 two, wave 7 one.

__global__ __launch_bounds__(NTHR, 2)
void lstm_mfma(const float* __restrict__ z,
               const float* __restrict__ c0f, const float* __restrict__ m0f,
               const float* __restrict__ c0b, const float* __restrict__ m0b,
               const float* __restrict__ Wf, const float* __restrict__ bfv,
               const float* __restrict__ Pf,
               const float* __restrict__ Wb, const float* __restrict__ bbv,
               const float* __restrict__ Pb,
               float* __restrict__ out)
{
  __shared__ __align__(16) u32  xt[10*256];   // x~ A-frags (10 KiB)
  __shared__ __align__(16) u32  hf[4*256];    // h  A-frags (4 KiB)
  __shared__ float ga[16*401];                // activated gates, stride 401
  __shared__ float cst[1600];                 // cell state, idx = s*16+m
  __shared__ float bias_l[400];

  const int tid = threadIdx.x, wv = tid>>6, lane = tid&63;
  const int l15 = lane&15, lg = lane>>4;
  const int dir = blockIdx.x>>3, seq0 = (blockIdx.x&7)*16;

  const float* W  = dir?Wb:Wf;  const float* bv = dir?bbv:bfv;
  const float* P  = dir?Pb:Pf;  const float* c0 = dir?c0b:c0f;
  const float* m0 = dir?m0b:m0f;

  const int ngt = (wv==0)?4:3;
  const int gnt[4] = {wv, wv+8, wv+16, 24};
  const int npt = (wv==0)?0:((wv==7)?1:2);
  const int pnt0 = 2*(wv-1);

  // ---- stage gate W fragments (-> AGPR-resident) ----
  f16x8 wg[4][10];
  #pragma unroll
  for (int i=0;i<4;++i) if (i<ngt) {
    const int n = gnt[i]*16 + l15;
    #pragma unroll
    for (int kt=0;kt<10;++kt) {
      f16x8 v;
      #pragma unroll
      for (int e=0;e<8;++e) {
        int k = kt*32 + lg*8 + e;
        v[e] = (_Float16)((k<300)? W[(size_t)k*400+n] : 0.f);
      }
      wg[i][kt]=v;
    }
  }
  // ---- stage proj P fragments ----
  f16x8 pw[2][4];
  #pragma unroll
  for (int i=0;i<2;++i) if (i<npt) {
    const int n = (pnt0+i)*16 + l15;
    #pragma unroll
    for (int kt=0;kt<4;++kt) {
      f16x8 v;
      #pragma unroll
      for (int e=0;e<8;++e) {
        int k = kt*32 + lg*8 + e;
        v[e] = (_Float16)((k<100 && n<200)? P[(size_t)k*200+n] : 0.f);
      }
      pw[i][kt]=v;
    }
  }

  // ---- init LDS ----
  for (int i=tid;i<2560;i+=NTHR) xt[i]=0u;
  for (int i=tid;i<1024;i+=NTHR) hf[i]=0u;
  if (tid<400) bias_l[tid] = bv[tid] + ((tid/100)==2 ? 1.0f : 0.0f);
  for (int i=tid;i<1600;i+=NTHR) { int s=i>>4, m=i&15; cst[i] = c0[(size_t)(seq0+m)*100+s]; }
  __syncthreads();
  {
    const int tt0 = dir?(TB-1):0;
    for (int i=tid;i<1600;i+=NTHR) {           // x(t0): i = m*100+xk
      int m=i/100, xk=i%100;
      float v = z[(size_t)(seq0+m)*40000 + (size_t)tt0*100 + xk];
      ((u16*)xt)[(xk>>5)*512 + (m|(((xk>>3)&3)<<4))*8 + (xk&7)] = h16(v);
    }
    for (int i=tid;i<3200;i+=NTHR) {           // m0: i = m*200+n -> k=100+n
      int m=i/200, n=i%200, k=100+n;
      float v = m0[(size_t)(seq0+m)*200+n];
      ((u16*)xt)[(k>>5)*512 + (m|(((k>>3)&3)<<4))*8 + (k&7)] = h16(v);
    }
  }
  __syncthreads();

  for (int t=0;t<TB;++t) {
    const int tt = dir?(TB-1-t):t;

    // x(t+1) prefetch to regs (consumed in phase C)
    float xpre[4];
    if (t+1<TB && tid<400) {
      const int tn = dir?(TB-2-t):(t+1);
      #pragma unroll
      for (int u=0;u<4;++u) {
        int i = tid+400*u; int m=i/100, xk=i%100;
        xpre[u] = z[(size_t)(seq0+m)*40000 + (size_t)tn*100 + xk];
      }
    }

    // (G) gates: A-frags from LDS, MFMA vs AGPR weights, fused activation
    f16x8 af[10];
    #pragma unroll
    for (int kt=0;kt<10;++kt)
      af[kt] = *reinterpret_cast<const f16x8*>(&xt[kt*256 + lane*4]);
    #pragma unroll
    for (int i=0;i<4;++i) if (i<ngt) {
      f32x4 acc = {0.f,0.f,0.f,0.f};
      #pragma unroll
      for (int kt=0;kt<10;++kt)
        acc = __builtin_amdgcn_mfma_f32_16x16x32_f16(af[kt], wg[i][kt], acc, 0,0,0);
      const int n = gnt[i]*16 + l15;
      const int g = n/100;                      // 0:i 1:j 2:f 3:o
      const float bb = bias_l[n];
      #pragma unroll
      for (int r=0;r<4;++r) {
        float a = acc[r] + bb;
        float arg = (g==1) ? a+a : a;           // tanh(x)=2*sig(2x)-1
        float v = sigf(arg);
        float res = (g==1) ? (2.0f*v-1.0f) : v;
        ga[(lg*4+r)*401 + n] = res;
      }
    }
    __syncthreads();                            // 1: ga ready

    // (C) cell update + h-frag write; x(t+1) into xt
    if (tid<400) {
      #pragma unroll
      for (int u=0;u<4;++u) {
        int c = tid+400*u; int s=c>>4, m=c&15;
        float I=ga[m*401+s], J=ga[m*401+100+s], Fg=ga[m*401+200+s], O=ga[m*401+300+s];
        float cc = Fg*cst[c] + I*J; cst[c]=cc;
        float h = O*tanhf_(cc);
        ((u16*)hf)[(s>>5)*512 + (m|(((s>>3)&3)<<4))*8 + (s&7)] = h16(h);
      }
      if (t+1<TB) {
        #pragma unroll
        for (int u=0;u<4;++u) {
          int i=tid+400*u; int m=i/100, xk=i%100;
          ((u16*)xt)[(xk>>5)*512 + (m|(((xk>>3)&3)<<4))*8 + (xk&7)] = h16(xpre[u]);
        }
      }
    }
    __syncthreads();                            // 2: hf ready

    // (P) projection MFMA + out store + m back into xt (k=100+fc)
    #pragma unroll
    for (int i=0;i<2;++i) if (i<npt) {
      f32x4 acc = {0.f,0.f,0.f,0.f};
      #pragma unroll
      for (int kt=0;kt<4;++kt) {
        f16x8 hfr = *reinterpret_cast<const f16x8*>(&hf[kt*256 + lane*4]);
        acc = __builtin_amdgcn_mfma_f32_16x16x32_f16(hfr, pw[i][kt], acc, 0,0,0);
      }
      const int fc = (pnt0+i)*16 + l15;
      if (fc<200) {
        #pragma unroll
        for (int r=0;r<4;++r) {
          int m = lg*4+r;
          float mv = acc[r];
          __builtin_nontemporal_store(mv,
              out + (size_t)(seq0+m)*OUTROW + (size_t)tt*400 + dir*200 + fc);
          int k = 100+fc;
          ((u16*)xt)[(k>>5)*512 + (m|(((k>>3)&3)<<4))*8 + (k&7)] = h16(mv);
        }
      }
    }
    __syncthreads();                            // 3: xt ready for next step
  }
}

extern "C" void kernel_launch(void* const* d_in, const int* in_sizes, int n_in,
                              void* d_out, int out_size, void* d_ws, size_t ws_size,
                              hipStream_t stream) {
  (void)in_sizes; (void)n_in; (void)out_size; (void)d_ws; (void)ws_size;
  lstm_mfma<<<GRID, NTHR, 0, stream>>>((const float*)d_in[0],
      (const float*)d_in[1], (const float*)d_in[2],
      (const float*)d_in[3], (const float*)d_in[4],
      (const float*)d_in[5], (const float*)d_in[6], (const float*)d_in[7],
      (const float*)d_in[8], (const float*)d_in[9], (const float*)d_in[10],
      (float*)d_out);
}